// Round 3
// baseline (382.978 us; speedup 1.0000x reference)
//
#include <hip/hip_runtime.h>
#include <hip/hip_bf16.h>

// 2-layer GCN on MI355X, round 3.
// - agg1 (4-ch aggregate) built by edge-parallel fp32 atomics fused into CSR fill.
// - h1 is NEVER materialized: layer-2 recomputes h1[s][c] per message from the
//   L2-resident agg1[s] (16B broadcast) + W1 column in registers.
// - layer-2 64x64 transform done with MFMA (bf16) on 16-node LDS tiles.
// 6 dispatches total (was 9).

constexpr int NN = 50000;
constexpr int NE = 800000;
constexpr int NB_SCAN = (NN + 255) / 256;  // 196
constexpr int NB_TILE = 3128;              // ceil(50000/16) -> 50048 padded rows

typedef __attribute__((ext_vector_type(8))) short bf16x8;
typedef __attribute__((ext_vector_type(4))) float f32x4;

#define ALIGN_UP(x, a) (((x) + (a) - 1) / (a) * (a))

// Count in-degree (4 edges/thread); block 0 also builds w2t[c][k] = bf16(W2[k][c]).
__global__ void count_deg(const int* __restrict__ dst, int* __restrict__ cnt,
                          const float* __restrict__ W2,
                          __hip_bfloat16* __restrict__ w2t) {
    int i = blockIdx.x * 256 + threadIdx.x;
    if (i < NE / 4) {
        int4 d = reinterpret_cast<const int4*>(dst)[i];
        atomicAdd(&cnt[d.x], 1);
        atomicAdd(&cnt[d.y], 1);
        atomicAdd(&cnt[d.z], 1);
        atomicAdd(&cnt[d.w], 1);
    }
    if (blockIdx.x == 0) {
        for (int idx = threadIdx.x; idx < 4096; idx += 256) {
            int c = idx >> 6, k = idx & 63;
            w2t[idx] = __float2bfloat16(W2[k * 64 + c]);
        }
    }
}

// Per-256-chunk exclusive scan of cnt; block totals to bsum; dinv = rsqrt(deg+1).
__global__ void scanA(const int* __restrict__ cnt, float* __restrict__ dinv,
                      int* __restrict__ off, int* __restrict__ bsum) {
    __shared__ int s[256];
    int tid = threadIdx.x;
    int i = blockIdx.x * 256 + tid;
    int v = (i < NN) ? cnt[i] : 0;
    if (i < NN) dinv[i] = rsqrtf((float)(v + 1));
    s[tid] = v;
    __syncthreads();
#pragma unroll
    for (int o = 1; o < 256; o <<= 1) {
        int t = (tid >= o) ? s[tid - o] : 0;
        __syncthreads();
        s[tid] += t;
        __syncthreads();
    }
    if (i < NN) off[i] = s[tid] - v;
    if (tid == 255) bsum[blockIdx.x] = s[255];
}

// Each block redundantly scans bsum (196 vals) in LDS, finalizes off+cursor,
// and seeds agg4 with the self-loop term x[n]*dinv[n]^2.
__global__ void scanBC(const int* __restrict__ bsum, int* __restrict__ off,
                       int* __restrict__ cursor, const float* __restrict__ dinv,
                       const float* __restrict__ x, float4* __restrict__ agg4) {
    __shared__ int s[256], e[256];
    int tid = threadIdx.x;
    int v = (tid < NB_SCAN) ? bsum[tid] : 0;
    s[tid] = v;
    __syncthreads();
#pragma unroll
    for (int o = 1; o < 256; o <<= 1) {
        int t = (tid >= o) ? s[tid - o] : 0;
        __syncthreads();
        s[tid] += t;
        __syncthreads();
    }
    e[tid] = s[tid] - v;
    __syncthreads();
    int bofs = e[blockIdx.x];
    int i = blockIdx.x * 256 + tid;
    if (i < NN) {
        int o2 = off[i] + bofs;
        off[i] = o2;
        cursor[i] = o2;
        float di = dinv[i];
        float sl = di * di;
        float4 xs = reinterpret_cast<const float4*>(x)[i];
        agg4[i] = make_float4(xs.x * sl, xs.y * sl, xs.z * sl, xs.w * sl);
    }
    if (i == 0) off[NN] = NE;
}

// CSR fill (src only; norm recomputed later from dinv) + layer-1 scatter-agg:
// agg4[d] += x[s] * dinv[s]*dinv[d]   (4 fp32 atomics/edge).
__global__ void fill_agg(const int* __restrict__ src, const int* __restrict__ dst,
                         const float* __restrict__ dinv, int* __restrict__ cursor,
                         int* __restrict__ csr, const float* __restrict__ x,
                         float* __restrict__ agg4) {
    int i = blockIdx.x * 256 + threadIdx.x;
    if (i >= NE) return;
    int s = src[i], d = dst[i];
    float nrm = dinv[s] * dinv[d];
    int pos = atomicAdd(&cursor[d], 1);
    csr[pos] = s;
    float4 xs = reinterpret_cast<const float4*>(x)[s];
    atomicAdd(&agg4[d * 4 + 0], xs.x * nrm);
    atomicAdd(&agg4[d * 4 + 1], xs.y * nrm);
    atomicAdd(&agg4[d * 4 + 2], xs.z * nrm);
    atomicAdd(&agg4[d * 4 + 3], xs.w * nrm);
}

// Layer 2, fully fused: 1 wave per 16-node tile.
// Phase A (per node, lane = h1-channel): acc_c = sum_e relu(h1[s][c])*nrm + self,
//   with h1[s][c] recomputed from agg4[s] (16B L2 broadcast) and W1 col in regs.
//   acc -> bf16 LDS tile [16][72] (padded: conflict-free MFMA reads).
// Phase B: out[16x64] = relu(tile[16x64] @ W2 + b2) via 8x mfma 16x16x32 bf16.
__global__ __launch_bounds__(64) void gcn_layer2_mfma(
        const float4* __restrict__ agg4, const int* __restrict__ off,
        const int* __restrict__ csr, const float* __restrict__ dinv,
        const float* __restrict__ W1, const float* __restrict__ b1,
        const __hip_bfloat16* __restrict__ w2t, const float* __restrict__ b2,
        float* __restrict__ out) {
    __shared__ __hip_bfloat16 tile[16][72];
    int lane = threadIdx.x;
    int base = blockIdx.x * 16;
    float w0 = W1[lane], w1 = W1[64 + lane], w2 = W1[128 + lane], w3 = W1[192 + lane];
    float b1c = b1[lane];

    for (int r = 0; r < 16; ++r) {
        int node = base + r;
        float acc = 0.f;
        if (node < NN) {
            float di = dinv[node];
            float4 a = agg4[node];
            float hs = fmaf(a.x, w0, fmaf(a.y, w1, fmaf(a.z, w2, fmaf(a.w, w3, b1c))));
            acc = fmaxf(hs, 0.f) * (di * di);  // self-loop message
            int j = off[node], end = off[node + 1];
            for (; j + 3 < end; j += 4) {
                int s0 = csr[j], s1 = csr[j + 1], s2 = csr[j + 2], s3 = csr[j + 3];
                float4 a0 = agg4[s0], a1 = agg4[s1], a2 = agg4[s2], a3 = agg4[s3];
                float n0 = dinv[s0] * di, n1 = dinv[s1] * di;
                float n2 = dinv[s2] * di, n3 = dinv[s3] * di;
                float h0 = fmaf(a0.x, w0, fmaf(a0.y, w1, fmaf(a0.z, w2, fmaf(a0.w, w3, b1c))));
                float h1v = fmaf(a1.x, w0, fmaf(a1.y, w1, fmaf(a1.z, w2, fmaf(a1.w, w3, b1c))));
                float h2v = fmaf(a2.x, w0, fmaf(a2.y, w1, fmaf(a2.z, w2, fmaf(a2.w, w3, b1c))));
                float h3v = fmaf(a3.x, w0, fmaf(a3.y, w1, fmaf(a3.z, w2, fmaf(a3.w, w3, b1c))));
                acc = fmaf(fmaxf(h0, 0.f), n0, acc);
                acc = fmaf(fmaxf(h1v, 0.f), n1, acc);
                acc = fmaf(fmaxf(h2v, 0.f), n2, acc);
                acc = fmaf(fmaxf(h3v, 0.f), n3, acc);
            }
            for (; j < end; ++j) {
                int s0 = csr[j];
                float4 a0 = agg4[s0];
                float h0 = fmaf(a0.x, w0, fmaf(a0.y, w1, fmaf(a0.z, w2, fmaf(a0.w, w3, b1c))));
                acc = fmaf(fmaxf(h0, 0.f), dinv[s0] * di, acc);
            }
        }
        tile[r][lane] = __float2bfloat16(acc);
    }
    __syncthreads();

    // MFMA: A lane layout row=lane&15, k=(lane>>4)*8..+7 (+32 for 2nd k-step);
    // B from w2t[col][k] (contiguous in k); C/D: col=lane&15, row=(lane>>4)*4+reg.
    int g = lane >> 4, c16 = lane & 15;
    bf16x8 a0 = *reinterpret_cast<const bf16x8*>(&tile[c16][g * 8]);
    bf16x8 a1 = *reinterpret_cast<const bf16x8*>(&tile[c16][32 + g * 8]);
#pragma unroll
    for (int ct = 0; ct < 4; ++ct) {
        int col = ct * 16 + c16;
        bf16x8 bb0 = *reinterpret_cast<const bf16x8*>(w2t + col * 64 + g * 8);
        bf16x8 bb1 = *reinterpret_cast<const bf16x8*>(w2t + col * 64 + 32 + g * 8);
        f32x4 acc = {0.f, 0.f, 0.f, 0.f};
        acc = __builtin_amdgcn_mfma_f32_16x16x32_bf16(a0, bb0, acc, 0, 0, 0);
        acc = __builtin_amdgcn_mfma_f32_16x16x32_bf16(a1, bb1, acc, 0, 0, 0);
        float b2v = b2[col];
#pragma unroll
        for (int rg = 0; rg < 4; ++rg) {
            int node = base + g * 4 + rg;
            if (node < NN) out[node * 64 + col] = fmaxf(acc[rg] + b2v, 0.f);
        }
    }
}

extern "C" void kernel_launch(void* const* d_in, const int* in_sizes, int n_in,
                              void* d_out, int out_size, void* d_ws, size_t ws_size,
                              hipStream_t stream) {
    const float* x  = (const float*)d_in[0];
    const int*   ei = (const int*)d_in[1];  // [2, NE]: src row then dst row
    const float* W1 = (const float*)d_in[2];
    const float* b1 = (const float*)d_in[3];
    const float* W2 = (const float*)d_in[4];
    const float* b2 = (const float*)d_in[5];
    float* out = (float*)d_out;
    const int* src = ei;
    const int* dst = ei + NE;

    char* w = (char*)d_ws;
    auto take = [&](size_t bytes) { char* p = w; w += ALIGN_UP(bytes, 256); return p; };
    int*   cnt    = (int*)  take((size_t)NN * 4);
    float* dinv   = (float*)take((size_t)NN * 4);
    int*   off    = (int*)  take((size_t)(NN + 1) * 4);
    int*   cursor = (int*)  take((size_t)NN * 4);
    int*   bsum   = (int*)  take(256 * 4);
    int*   csr    = (int*)  take((size_t)NE * 4);
    float* agg4   = (float*)take((size_t)NN * 16);
    __hip_bfloat16* w2t = (__hip_bfloat16*)take(4096 * 2);

    const int NB_EDGE = (NE + 255) / 256;        // 3125
    const int NB_CNT  = (NE / 4 + 255) / 256;    // 782

    hipMemsetAsync(cnt, 0, (size_t)NN * 4, stream);
    count_deg<<<NB_CNT, 256, 0, stream>>>(dst, cnt, W2, w2t);
    scanA<<<NB_SCAN, 256, 0, stream>>>(cnt, dinv, off, bsum);
    scanBC<<<NB_SCAN, 256, 0, stream>>>(bsum, off, cursor, dinv, x, (float4*)agg4);
    fill_agg<<<NB_EDGE, 256, 0, stream>>>(src, dst, dinv, cursor, csr, x, agg4);
    gcn_layer2_mfma<<<NB_TILE, 64, 0, stream>>>((const float4*)agg4, off, csr, dinv,
                                                W1, b1, w2t, b2, out);
}

// Round 4
// 197.469 us; speedup vs baseline: 1.9394x; 1.9394x over previous
//
#include <hip/hip_runtime.h>
#include <hip/hip_bf16.h>

// 2-layer GCN on MI355X, round 4.
// Lesson from r3: each scattered global atomic costs ~32B of HBM write-through
// traffic -> minimize atomic COUNT. This version uses exactly ONE atomic per
// edge (bucket-CSR fill); no count/scan kernels, no fp32 atomics.
//   memset cursor -> fill_buckets(+w2t) -> finalize_dinv -> agg_gather
//   -> gcn_layer2_mfma (recompute-h1 + MFMA epilogue, verified in r3).

constexpr int NN = 50000;
constexpr int NE = 800000;
constexpr int CAP = 64;        // bucket capacity; in-deg ~ Poisson(16), P(>=64) ~ 1e-20
constexpr int NB_TILE = 3128;  // ceil(50000/16)

typedef __attribute__((ext_vector_type(8))) short bf16x8;
typedef __attribute__((ext_vector_type(4))) float f32x4;

#define ALIGN_UP(x, a) (((x) + (a) - 1) / (a) * (a))

// One atomic per edge: slot = cursor[d]++; slots[d*CAP+slot] = s.
// Block 0 also builds w2t[c][k] = bf16(W2[k][c]) for the MFMA B-operand.
__global__ __launch_bounds__(256) void fill_buckets(
        const int* __restrict__ src, const int* __restrict__ dst,
        int* __restrict__ cursor, int* __restrict__ slots,
        const float* __restrict__ W2, __hip_bfloat16* __restrict__ w2t) {
    int i = blockIdx.x * 256 + threadIdx.x;
    if (i < NE) {
        int s = src[i], d = dst[i];
        int pos = atomicAdd(&cursor[d], 1);
        slots[d * CAP + pos] = s;
    }
    if (blockIdx.x == 0) {
        for (int idx = threadIdx.x; idx < 4096; idx += 256) {
            int c = idx >> 6, k = idx & 63;
            w2t[idx] = __float2bfloat16(W2[k * 64 + c]);
        }
    }
}

__global__ __launch_bounds__(256) void finalize_dinv(const int* __restrict__ cursor,
                                                     float* __restrict__ dinv) {
    int i = blockIdx.x * 256 + threadIdx.x;
    if (i < NN) dinv[i] = rsqrtf((float)(cursor[i] + 1));
}

// agg4[n] = x[n]*dinv[n]^2 + dinv[n] * sum_slots x[s]*dinv[s].
// 16 lanes per node, 4 nodes per wave; butterfly reduce within 16-lane groups.
__global__ __launch_bounds__(256) void agg_gather(
        const float4* __restrict__ x, const int* __restrict__ cursor,
        const int* __restrict__ slots, const float* __restrict__ dinv,
        float4* __restrict__ agg4) {
    int tid = threadIdx.x;
    int lane = tid & 63;
    int grp = lane >> 4;   // node-in-wave 0..3
    int t = lane & 15;     // lane-in-group
    int node = ((blockIdx.x * 256 + tid) >> 6) * 4 + grp;  // grid sized exactly
    int deg = cursor[node];
    float ax = 0.f, ay = 0.f, az = 0.f, aw = 0.f;
    const int* sl = slots + node * CAP;
    for (int j = t; j < deg; j += 16) {
        int s = sl[j];
        float4 xs = x[s];
        float w = dinv[s];
        ax = fmaf(xs.x, w, ax);
        ay = fmaf(xs.y, w, ay);
        az = fmaf(xs.z, w, az);
        aw = fmaf(xs.w, w, aw);
    }
#pragma unroll
    for (int o = 8; o >= 1; o >>= 1) {
        ax += __shfl_xor(ax, o);
        ay += __shfl_xor(ay, o);
        az += __shfl_xor(az, o);
        aw += __shfl_xor(aw, o);
    }
    if (t == 0) {
        float di = dinv[node];
        float sl2 = di * di;
        float4 xs = x[node];
        agg4[node] = make_float4(fmaf(di, ax, xs.x * sl2),
                                 fmaf(di, ay, xs.y * sl2),
                                 fmaf(di, az, xs.z * sl2),
                                 fmaf(di, aw, xs.w * sl2));
    }
}

// Layer 2 fully fused, 1 wave per 16-node tile (structure verified in r3).
// Phase A (lane = h1-channel): acc_c = self + sum_e relu(h1[s][c]) * nrm_e,
//   h1[s][c] recomputed from agg4[s] (16B L2-resident broadcast) + W1 col regs.
// Phase B: out[16x64] = relu(tile @ W2 + b2) via 2x mfma 16x16x32 bf16 per col-tile.
__global__ __launch_bounds__(64) void gcn_layer2_mfma(
        const float4* __restrict__ agg4, const int* __restrict__ cursor,
        const int* __restrict__ slots, const float* __restrict__ dinv,
        const float* __restrict__ W1, const float* __restrict__ b1,
        const __hip_bfloat16* __restrict__ w2t, const float* __restrict__ b2,
        float* __restrict__ out) {
    __shared__ __hip_bfloat16 tile[16][72];
    int lane = threadIdx.x;
    int base = blockIdx.x * 16;
    float w0 = W1[lane], w1 = W1[64 + lane], w2 = W1[128 + lane], w3 = W1[192 + lane];
    float b1c = b1[lane];

    for (int r = 0; r < 16; ++r) {
        int node = base + r;
        float acc = 0.f;
        if (node < NN) {
            float di = dinv[node];
            float4 a = agg4[node];
            float hs = fmaf(a.x, w0, fmaf(a.y, w1, fmaf(a.z, w2, fmaf(a.w, w3, b1c))));
            acc = fmaxf(hs, 0.f) * (di * di);  // self-loop message
            int deg = cursor[node];
            const int* sl = slots + node * CAP;
            int j = 0;
            for (; j + 3 < deg; j += 4) {
                int4 s4 = *reinterpret_cast<const int4*>(sl + j);
                float4 a0 = agg4[s4.x], a1 = agg4[s4.y];
                float4 a2 = agg4[s4.z], a3 = agg4[s4.w];
                float n0 = dinv[s4.x] * di, n1 = dinv[s4.y] * di;
                float n2 = dinv[s4.z] * di, n3 = dinv[s4.w] * di;
                float h0 = fmaf(a0.x, w0, fmaf(a0.y, w1, fmaf(a0.z, w2, fmaf(a0.w, w3, b1c))));
                float h1v = fmaf(a1.x, w0, fmaf(a1.y, w1, fmaf(a1.z, w2, fmaf(a1.w, w3, b1c))));
                float h2v = fmaf(a2.x, w0, fmaf(a2.y, w1, fmaf(a2.z, w2, fmaf(a2.w, w3, b1c))));
                float h3v = fmaf(a3.x, w0, fmaf(a3.y, w1, fmaf(a3.z, w2, fmaf(a3.w, w3, b1c))));
                acc = fmaf(fmaxf(h0, 0.f), n0, acc);
                acc = fmaf(fmaxf(h1v, 0.f), n1, acc);
                acc = fmaf(fmaxf(h2v, 0.f), n2, acc);
                acc = fmaf(fmaxf(h3v, 0.f), n3, acc);
            }
            for (; j < deg; ++j) {
                int s0 = sl[j];
                float4 a0 = agg4[s0];
                float h0 = fmaf(a0.x, w0, fmaf(a0.y, w1, fmaf(a0.z, w2, fmaf(a0.w, w3, b1c))));
                acc = fmaf(fmaxf(h0, 0.f), dinv[s0] * di, acc);
            }
        }
        tile[r][lane] = __float2bfloat16(acc);
    }
    __syncthreads();

    // MFMA (layouts verified end-to-end in r3).
    int g = lane >> 4, c16 = lane & 15;
    bf16x8 a0 = *reinterpret_cast<const bf16x8*>(&tile[c16][g * 8]);
    bf16x8 a1 = *reinterpret_cast<const bf16x8*>(&tile[c16][32 + g * 8]);
#pragma unroll
    for (int ct = 0; ct < 4; ++ct) {
        int col = ct * 16 + c16;
        bf16x8 bb0 = *reinterpret_cast<const bf16x8*>(w2t + col * 64 + g * 8);
        bf16x8 bb1 = *reinterpret_cast<const bf16x8*>(w2t + col * 64 + 32 + g * 8);
        f32x4 acc = {0.f, 0.f, 0.f, 0.f};
        acc = __builtin_amdgcn_mfma_f32_16x16x32_bf16(a0, bb0, acc, 0, 0, 0);
        acc = __builtin_amdgcn_mfma_f32_16x16x32_bf16(a1, bb1, acc, 0, 0, 0);
        float b2v = b2[col];
#pragma unroll
        for (int rg = 0; rg < 4; ++rg) {
            int node = base + g * 4 + rg;
            if (node < NN) out[node * 64 + col] = fmaxf(acc[rg] + b2v, 0.f);
        }
    }
}

extern "C" void kernel_launch(void* const* d_in, const int* in_sizes, int n_in,
                              void* d_out, int out_size, void* d_ws, size_t ws_size,
                              hipStream_t stream) {
    const float* x  = (const float*)d_in[0];
    const int*   ei = (const int*)d_in[1];  // [2, NE]: src row then dst row
    const float* W1 = (const float*)d_in[2];
    const float* b1 = (const float*)d_in[3];
    const float* W2 = (const float*)d_in[4];
    const float* b2 = (const float*)d_in[5];
    float* out = (float*)d_out;
    const int* src = ei;
    const int* dst = ei + NE;

    char* w = (char*)d_ws;
    auto take = [&](size_t bytes) { char* p = w; w += ALIGN_UP(bytes, 256); return p; };
    int*   cursor = (int*)  take((size_t)NN * 4);
    float* dinv   = (float*)take((size_t)NN * 4);
    int*   slots  = (int*)  take((size_t)NN * CAP * 4);  // 12.8 MB
    float* agg4   = (float*)take((size_t)NN * 16);
    __hip_bfloat16* w2t = (__hip_bfloat16*)take(4096 * 2);

    const int NB_EDGE = (NE + 255) / 256;  // 3125
    const int NB_NODE = (NN + 255) / 256;  // 196
    const int NB_AGG  = NN / 16;           // 3125 blocks x 4 waves x 4 nodes

    hipMemsetAsync(cursor, 0, (size_t)NN * 4, stream);
    fill_buckets<<<NB_EDGE, 256, 0, stream>>>(src, dst, cursor, slots, W2, w2t);
    finalize_dinv<<<NB_NODE, 256, 0, stream>>>(cursor, dinv);
    agg_gather<<<NB_AGG, 256, 0, stream>>>((const float4*)x, cursor, slots, dinv,
                                           (float4*)agg4);
    gcn_layer2_mfma<<<NB_TILE, 64, 0, stream>>>((const float4*)agg4, cursor, slots,
                                                dinv, W1, b1, w2t, b2, out);
}

// Round 5
// 171.273 us; speedup vs baseline: 2.2361x; 1.1529x over previous
//
#include <hip/hip_runtime.h>
#include <hip/hip_bf16.h>

// 2-layer GCN on MI355X, round 5.
// r4 lesson: layer2 was latency-bound at 26% occupancy (1-wave blocks, 16
// serial nodes/wave). Now: 4-wave blocks per 16-node tile (4 nodes/wave,
// wave-split MFMA epilogue), dinv recomputed from cursor (finalize kernel
// deleted). 4 dispatches: memset, fill_buckets(+w2t), agg_gather, layer2.

constexpr int NN = 50000;
constexpr int NE = 800000;
constexpr int CAP = 64;        // in-deg ~ Poisson(16), P(>=64) ~ 1e-20
constexpr int NB_TILE = 3128;  // ceil(50000/16), one tile per 256-thread block

typedef __attribute__((ext_vector_type(8))) short bf16x8;
typedef __attribute__((ext_vector_type(4))) float f32x4;

#define ALIGN_UP(x, a) (((x) + (a) - 1) / (a) * (a))

// One atomic per edge: slot = cursor[d]++; slots[d*CAP+slot] = s.
// 4 edges/thread via int4. Block 0 also builds w2t[c][k] = bf16(W2[k][c]).
__global__ __launch_bounds__(256) void fill_buckets(
        const int4* __restrict__ src4, const int4* __restrict__ dst4,
        int* __restrict__ cursor, int* __restrict__ slots,
        const float* __restrict__ W2, __hip_bfloat16* __restrict__ w2t) {
    int i = blockIdx.x * 256 + threadIdx.x;
    if (i < NE / 4) {
        int4 s = src4[i], d = dst4[i];
        int p0 = atomicAdd(&cursor[d.x], 1);
        slots[d.x * CAP + p0] = s.x;
        int p1 = atomicAdd(&cursor[d.y], 1);
        slots[d.y * CAP + p1] = s.y;
        int p2 = atomicAdd(&cursor[d.z], 1);
        slots[d.z * CAP + p2] = s.z;
        int p3 = atomicAdd(&cursor[d.w], 1);
        slots[d.w * CAP + p3] = s.w;
    }
    if (blockIdx.x == 0) {
        for (int idx = threadIdx.x; idx < 4096; idx += 256) {
            int c = idx >> 6, k = idx & 63;
            w2t[idx] = __float2bfloat16(W2[k * 64 + c]);
        }
    }
}

// agg4[n] = x[n]*dinv[n]^2 + dinv[n] * sum_slots x[s]*dinv[s].
// 16 lanes per node, 4 nodes per wave; dinv recomputed from cursor.
__global__ __launch_bounds__(256) void agg_gather(
        const float4* __restrict__ x, const int* __restrict__ cursor,
        const int* __restrict__ slots, float4* __restrict__ agg4) {
    int tid = threadIdx.x;
    int lane = tid & 63;
    int grp = lane >> 4;   // node-in-wave 0..3
    int t = lane & 15;     // lane-in-group
    int node = ((blockIdx.x * 256 + tid) >> 6) * 4 + grp;  // exact grid
    int deg = cursor[node];
    float ax = 0.f, ay = 0.f, az = 0.f, aw = 0.f;
    const int* sl = slots + node * CAP;
    for (int j = t; j < deg; j += 16) {
        int s = sl[j];
        float4 xs = x[s];
        float w = rsqrtf((float)(cursor[s] + 1));
        ax = fmaf(xs.x, w, ax);
        ay = fmaf(xs.y, w, ay);
        az = fmaf(xs.z, w, az);
        aw = fmaf(xs.w, w, aw);
    }
#pragma unroll
    for (int o = 8; o >= 1; o >>= 1) {
        ax += __shfl_xor(ax, o);
        ay += __shfl_xor(ay, o);
        az += __shfl_xor(az, o);
        aw += __shfl_xor(aw, o);
    }
    if (t == 0) {
        float di = rsqrtf((float)(deg + 1));
        float sl2 = di * di;
        float4 xs = x[node];
        agg4[node] = make_float4(fmaf(di, ax, xs.x * sl2),
                                 fmaf(di, ay, xs.y * sl2),
                                 fmaf(di, az, xs.z * sl2),
                                 fmaf(di, aw, xs.w * sl2));
    }
}

// Layer 2 fully fused; 256-thread block = 4 waves per 16-node tile.
// Phase A: wave wv aggregates rows wv*4..wv*4+3 (lane = h1-channel):
//   acc_c = self + sum_e relu(h1[s][c]) * nrm_e, h1 recomputed from
//   L2-resident agg4[s] + W1 column in registers. Rows -> bf16 LDS tile.
// Phase B: wave wv computes output col-tile ct=wv via 2x mfma 16x16x32 bf16.
__global__ __launch_bounds__(256) void gcn_layer2_mfma(
        const float4* __restrict__ agg4, const int* __restrict__ cursor,
        const int* __restrict__ slots, const float* __restrict__ W1,
        const float* __restrict__ b1, const __hip_bfloat16* __restrict__ w2t,
        const float* __restrict__ b2, float* __restrict__ out) {
    __shared__ __hip_bfloat16 tile[16][72];
    int tid = threadIdx.x;
    int wv = tid >> 6, lane = tid & 63;
    int base = blockIdx.x * 16;
    float w0 = W1[lane], w1 = W1[64 + lane], w2 = W1[128 + lane], w3 = W1[192 + lane];
    float b1c = b1[lane];

#pragma unroll
    for (int r = 0; r < 4; ++r) {
        int row = wv * 4 + r;
        int node = base + row;
        float acc = 0.f;
        if (node < NN) {
            int deg = cursor[node];
            float di = rsqrtf((float)(deg + 1));
            float4 a = agg4[node];
            float hs = fmaf(a.x, w0, fmaf(a.y, w1, fmaf(a.z, w2, fmaf(a.w, w3, b1c))));
            acc = fmaxf(hs, 0.f) * (di * di);  // self-loop message
            const int* sl = slots + node * CAP;
            int j = 0;
            for (; j + 3 < deg; j += 4) {
                int4 s4 = *reinterpret_cast<const int4*>(sl + j);
                float4 a0 = agg4[s4.x], a1 = agg4[s4.y];
                float4 a2 = agg4[s4.z], a3 = agg4[s4.w];
                float n0 = rsqrtf((float)(cursor[s4.x] + 1)) * di;
                float n1 = rsqrtf((float)(cursor[s4.y] + 1)) * di;
                float n2 = rsqrtf((float)(cursor[s4.z] + 1)) * di;
                float n3 = rsqrtf((float)(cursor[s4.w] + 1)) * di;
                float h0 = fmaf(a0.x, w0, fmaf(a0.y, w1, fmaf(a0.z, w2, fmaf(a0.w, w3, b1c))));
                float h1v = fmaf(a1.x, w0, fmaf(a1.y, w1, fmaf(a1.z, w2, fmaf(a1.w, w3, b1c))));
                float h2v = fmaf(a2.x, w0, fmaf(a2.y, w1, fmaf(a2.z, w2, fmaf(a2.w, w3, b1c))));
                float h3v = fmaf(a3.x, w0, fmaf(a3.y, w1, fmaf(a3.z, w2, fmaf(a3.w, w3, b1c))));
                acc = fmaf(fmaxf(h0, 0.f), n0, acc);
                acc = fmaf(fmaxf(h1v, 0.f), n1, acc);
                acc = fmaf(fmaxf(h2v, 0.f), n2, acc);
                acc = fmaf(fmaxf(h3v, 0.f), n3, acc);
            }
            for (; j < deg; ++j) {
                int s0 = sl[j];
                float4 a0 = agg4[s0];
                float h0 = fmaf(a0.x, w0, fmaf(a0.y, w1, fmaf(a0.z, w2, fmaf(a0.w, w3, b1c))));
                acc = fmaf(fmaxf(h0, 0.f), rsqrtf((float)(cursor[s0] + 1)) * di, acc);
            }
        }
        tile[row][lane] = __float2bfloat16(acc);
    }
    __syncthreads();

    // MFMA (fragment layouts verified end-to-end in r3/r4). Wave wv -> cols
    // wv*16..wv*16+15.
    int g = lane >> 4, c16 = lane & 15;
    bf16x8 a0 = *reinterpret_cast<const bf16x8*>(&tile[c16][g * 8]);
    bf16x8 a1 = *reinterpret_cast<const bf16x8*>(&tile[c16][32 + g * 8]);
    int col = wv * 16 + c16;
    bf16x8 bb0 = *reinterpret_cast<const bf16x8*>(w2t + col * 64 + g * 8);
    bf16x8 bb1 = *reinterpret_cast<const bf16x8*>(w2t + col * 64 + 32 + g * 8);
    f32x4 acc = {0.f, 0.f, 0.f, 0.f};
    acc = __builtin_amdgcn_mfma_f32_16x16x32_bf16(a0, bb0, acc, 0, 0, 0);
    acc = __builtin_amdgcn_mfma_f32_16x16x32_bf16(a1, bb1, acc, 0, 0, 0);
    float b2v = b2[col];
#pragma unroll
    for (int rg = 0; rg < 4; ++rg) {
        int node = base + g * 4 + rg;
        if (node < NN) out[node * 64 + col] = fmaxf(acc[rg] + b2v, 0.f);
    }
}

extern "C" void kernel_launch(void* const* d_in, const int* in_sizes, int n_in,
                              void* d_out, int out_size, void* d_ws, size_t ws_size,
                              hipStream_t stream) {
    const float* x  = (const float*)d_in[0];
    const int*   ei = (const int*)d_in[1];  // [2, NE]: src row then dst row
    const float* W1 = (const float*)d_in[2];
    const float* b1 = (const float*)d_in[3];
    const float* W2 = (const float*)d_in[4];
    const float* b2 = (const float*)d_in[5];
    float* out = (float*)d_out;
    const int* src = ei;
    const int* dst = ei + NE;

    char* w = (char*)d_ws;
    auto take = [&](size_t bytes) { char* p = w; w += ALIGN_UP(bytes, 256); return p; };
    int*   cursor = (int*)  take((size_t)NN * 4);
    int*   slots  = (int*)  take((size_t)NN * CAP * 4);  // 12.8 MB
    float* agg4   = (float*)take((size_t)NN * 16);
    __hip_bfloat16* w2t = (__hip_bfloat16*)take(4096 * 2);

    const int NB_FILL = (NE / 4 + 255) / 256;  // 782
    const int NB_AGG  = NN / 16;               // 3125

    hipMemsetAsync(cursor, 0, (size_t)NN * 4, stream);
    fill_buckets<<<NB_FILL, 256, 0, stream>>>((const int4*)src, (const int4*)dst,
                                              cursor, slots, W2, w2t);
    agg_gather<<<NB_AGG, 256, 0, stream>>>((const float4*)x, cursor, slots,
                                           (float4*)agg4);
    gcn_layer2_mfma<<<NB_TILE, 256, 0, stream>>>((const float4*)agg4, cursor, slots,
                                                 W1, b1, w2t, b2, out);
}